// Round 4
// baseline (24.841 us; speedup 1.0000x reference)
//
#include <hip/hip_runtime.h>

// Problem constants (from the reference file)
constexpr int kC = 3;
constexpr int kH = 2048;
constexpr int kW = 2048;
constexpr int kNB = 256;      // N_BOXES
constexpr int kHeight = 32;   // HEIGHT

typedef float f32x4 __attribute__((ext_vector_type(4)));

// One thread per 4 output columns of one (box b, row r); covers all 3 channels.
// Block = (64 col-threads) x (4 rows). Plain (cached) stores: img(48MB)+out(64MB)
// fit the 256MB Infinity Cache, so replays should run out of LLC, not HBM.
// Replicates the reference's float32 arithmetic exactly (fp contract off).
__global__ __launch_bounds__(256) void extract_kernel(
    const float* __restrict__ img,
    const float* __restrict__ boxes,
    const float* __restrict__ scale,
    float* __restrict__ out,
    int max_w)
{
#pragma clang fp contract(off)
    const int r = blockIdx.y * 4 + threadIdx.y;
    const int b = blockIdx.z;
    const int c0 = (blockIdx.x * 64 + threadIdx.x) * 4;
    if (c0 >= max_w) return;

    const float s = scale[0];
    const float* bx = boxes + b * 8;      // boxes[b, 4, 2]
    const float p0x = bx[0] / s, p0y = bx[1] / s;
    const float p1x = bx[2] / s, p1y = bx[3] / s;
    const float p2x = bx[4] / s, p2y = bx[5] / s;
    const float p3x = bx[6] / s, p3y = bx[7] / s;

    // h_dists = |p2-p1|, w_dists = |p1-p0|
    const float hdx = p2x - p1x, hdy = p2y - p1y;
    const float h_dist = sqrtf(hdx * hdx + hdy * hdy);
    const float wdx = p1x - p0x, wdy = p1y - p0y;
    const float w_dist = sqrtf(wdx * wdx + wdy * wdy);
    // widths = (32 * w / clip(h,1e-6)).astype(int32)  -> trunc toward zero
    const int width = (int)(32.0f * w_dist / fmaxf(h_dist, 1e-6f));
    const float curr_w = (float)width;

    // widths_out[b] = widths//8*8 + 8, stored as float at the tail of d_out
    if (r == 0 && c0 == 0) {
        out[(size_t)kNB * kC * kHeight * max_w + b] = (float)(width / 8 * 8 + 8);
    }

    const size_t ch_stride = (size_t)kHeight * max_w;
    // out[b][ch][r][c0..c0+3]
    const size_t obase = (((size_t)b * kC) * (size_t)kHeight + (size_t)r) * (size_t)max_w + (size_t)c0;

    f32x4 o0 = {0.f, 0.f, 0.f, 0.f};
    f32x4 o1 = {0.f, 0.f, 0.f, 0.f};
    f32x4 o2 = {0.f, 0.f, 0.f, 0.f};

    if (c0 < width) {
        const float y = (float)r / 31.0f;                    // rows/(height-1)
        const float omy = 1.0f - y;
        const float xden = fmaxf(curr_w - 1.0f, 1.0f);       // clip(w-1,1)
#pragma unroll
        for (int j = 0; j < 4; ++j) {
            const float cf = (float)(c0 + j);
            if (cf < curr_w) {
                const float x = cf / xden;
                const float omx = 1.0f - x;
                const float w00 = omx * omy;
                const float w10 = x * omy;
                const float w11 = x * y;
                const float w01 = omx * y;
                const float res_x = w00 * p0x + w10 * p1x + w11 * p2x + w01 * p3x;
                const float res_y = w00 * p0y + w10 * p1y + w11 * p2y + w01 * p3y;

                const float grid_c = res_x / 2047.0f * 2.0f - 1.0f;
                const float grid_r = res_y / 2047.0f * 2.0f - 1.0f;
                const float fix = rintf((grid_c + 1.0f) * 2047.0f * 0.5f);
                const float fiy = rintf((grid_r + 1.0f) * 2047.0f * 0.5f);
                const bool inb = (fix >= 0.0f) && (fix <= 2047.0f) &&
                                 (fiy >= 0.0f) && (fiy <= 2047.0f);
                const int ixc = (int)fminf(fmaxf(fix, 0.0f), 2047.0f);
                const int iyc = (int)fminf(fmaxf(fiy, 0.0f), 2047.0f);

                const size_t ipix = (size_t)iyc * kW + (size_t)ixc;
                const float v0 = img[ipix];
                const float v1 = img[(size_t)kH * kW + ipix];
                const float v2 = img[2 * (size_t)kH * kW + ipix];
                o0[j] = inb ? v0 : 0.0f;
                o1[j] = inb ? v1 : 0.0f;
                o2[j] = inb ? v2 : 0.0f;
            }
        }
    }

    // 16B-aligned (max_w % 8 == 0, c0 % 4 == 0) cached stores.
    *(f32x4*)(out + obase) = o0;
    *(f32x4*)(out + obase + ch_stride) = o1;
    *(f32x4*)(out + obase + 2 * ch_stride) = o2;
}

extern "C" void kernel_launch(void* const* d_in, const int* in_sizes, int n_in,
                              void* d_out, int out_size, void* d_ws, size_t ws_size,
                              hipStream_t stream) {
    const float* img   = (const float*)d_in[0];
    const float* boxes = (const float*)d_in[1];
    const float* scale = (const float*)d_in[2];
    float* out = (float*)d_out;

    // out_size = NB*C*HEIGHT*max_w + NB  ->  max_w recoverable on host.
    // max_w is a multiple of 8 by construction (w//8*8+8).
    const int max_w = (out_size - kNB) / (kNB * kC * kHeight);
    const int quads = max_w / 4;

    dim3 grid((quads + 63) / 64, kHeight / 4, kNB);
    extract_kernel<<<grid, dim3(64, 4, 1), 0, stream>>>(img, boxes, scale, out, max_w);
}

// Round 5
// 24.757 us; speedup vs baseline: 1.0034x; 1.0034x over previous
//
#include <hip/hip_runtime.h>

// Problem constants (from the reference file)
constexpr int kC = 3;
constexpr int kH = 2048;
constexpr int kW = 2048;
constexpr int kNB = 256;      // N_BOXES
constexpr int kHeight = 32;   // HEIGHT

typedef float f32x4 __attribute__((ext_vector_type(4)));

// Kernel 1: per-box parameters -> d_ws (16 floats/box), widths_out -> out tail.
// One-time cost; divides live here, not in the hot kernel.
__global__ __launch_bounds__(256) void boxprep_kernel(
    const float* __restrict__ boxes,
    const float* __restrict__ scale,
    float* __restrict__ params,
    float* __restrict__ out_tail)
{
    const int b = threadIdx.x;            // 256 boxes, 1 block
    const float s = scale[0];
    const float* bx = boxes + b * 8;
    float p[8];
#pragma unroll
    for (int k = 0; k < 8; ++k) p[k] = bx[k] / s;

    const float hdx = p[4] - p[2], hdy = p[5] - p[3];
    const float h_dist = sqrtf(hdx * hdx + hdy * hdy);
    const float wdx = p[2] - p[0], wdy = p[3] - p[1];
    const float w_dist = sqrtf(wdx * wdx + wdy * wdy);
    const int width = (int)(32.0f * w_dist / fmaxf(h_dist, 1e-6f));
    const float curr_w = (float)width;
    const float inv_xden = 1.0f / fmaxf(curr_w - 1.0f, 1.0f);

    float* pp = params + b * 16;
#pragma unroll
    for (int k = 0; k < 8; ++k) pp[k] = p[k];
    pp[8] = curr_w;
    pp[9] = inv_xden;

    out_tail[b] = (float)(width / 8 * 8 + 8);
}

// Kernel 2: one thread per 4 output columns of one (box b, row r), 3 channels.
// Division-free inner loop; box params come from d_ws (wave-uniform loads).
__global__ __launch_bounds__(64) void extract_kernel(
    const float* __restrict__ img,
    const float* __restrict__ params,
    float* __restrict__ out,
    int max_w)
{
    const int r = blockIdx.y;
    const int b = blockIdx.z;
    const int c0 = (blockIdx.x * 64 + threadIdx.x) * 4;
    if (c0 >= max_w) return;

    const float* pp = params + b * 16;    // uniform across the wave
    const float p0x = pp[0], p0y = pp[1];
    const float p1x = pp[2], p1y = pp[3];
    const float p2x = pp[4], p2y = pp[5];
    const float p3x = pp[6], p3y = pp[7];
    const float curr_w = pp[8];
    const float inv_xden = pp[9];

    const size_t ch_stride = (size_t)kHeight * max_w;
    const size_t obase = (((size_t)b * kC) * (size_t)kHeight + (size_t)r) * (size_t)max_w + (size_t)c0;

    f32x4 o0 = {0.f, 0.f, 0.f, 0.f};
    f32x4 o1 = {0.f, 0.f, 0.f, 0.f};
    f32x4 o2 = {0.f, 0.f, 0.f, 0.f};

    if ((float)c0 < curr_w) {
        const float y = (float)r / 31.0f;     // one precise div, wave-uniform
        const float omy = 1.0f - y;
        constexpr float invW1 = 1.0f / 2047.0f;
#pragma unroll
        for (int j = 0; j < 4; ++j) {
            const float cf = (float)(c0 + j);
            if (cf < curr_w) {
                const float x = cf * inv_xden;
                const float omx = 1.0f - x;
                const float w00 = omx * omy;
                const float w10 = x * omy;
                const float w11 = x * y;
                const float w01 = omx * y;
                const float res_x = w00 * p0x + w10 * p1x + w11 * p2x + w01 * p3x;
                const float res_y = w00 * p0y + w10 * p1y + w11 * p2y + w01 * p3y;

                const float grid_c = res_x * invW1 * 2.0f - 1.0f;
                const float grid_r = res_y * invW1 * 2.0f - 1.0f;
                const float fix = rintf((grid_c + 1.0f) * 2047.0f * 0.5f);
                const float fiy = rintf((grid_r + 1.0f) * 2047.0f * 0.5f);
                const bool inb = (fix >= 0.0f) && (fix <= 2047.0f) &&
                                 (fiy >= 0.0f) && (fiy <= 2047.0f);
                const int ixc = (int)fminf(fmaxf(fix, 0.0f), 2047.0f);
                const int iyc = (int)fminf(fmaxf(fiy, 0.0f), 2047.0f);

                const size_t ipix = (size_t)iyc * kW + (size_t)ixc;
                const float v0 = img[ipix];
                const float v1 = img[(size_t)kH * kW + ipix];
                const float v2 = img[2 * (size_t)kH * kW + ipix];
                o0[j] = inb ? v0 : 0.0f;
                o1[j] = inb ? v1 : 0.0f;
                o2[j] = inb ? v2 : 0.0f;
            }
        }
    }

    // 16B-aligned (max_w % 8 == 0, c0 % 4 == 0) stores.
    *(f32x4*)(out + obase) = o0;
    *(f32x4*)(out + obase + ch_stride) = o1;
    *(f32x4*)(out + obase + 2 * ch_stride) = o2;
}

extern "C" void kernel_launch(void* const* d_in, const int* in_sizes, int n_in,
                              void* d_out, int out_size, void* d_ws, size_t ws_size,
                              hipStream_t stream) {
    const float* img   = (const float*)d_in[0];
    const float* boxes = (const float*)d_in[1];
    const float* scale = (const float*)d_in[2];
    float* out = (float*)d_out;
    float* params = (float*)d_ws;         // 256 boxes * 16 floats = 16 KB

    // out_size = NB*C*HEIGHT*max_w + NB  ->  max_w recoverable on host.
    // max_w is a multiple of 8 by construction (w//8*8+8).
    const int max_w = (out_size - kNB) / (kNB * kC * kHeight);
    const int quads = max_w / 4;

    boxprep_kernel<<<1, kNB, 0, stream>>>(boxes, scale, params,
                                          out + (size_t)kNB * kC * kHeight * max_w);

    dim3 grid((quads + 63) / 64, kHeight, kNB);
    extract_kernel<<<grid, dim3(64, 1, 1), 0, stream>>>(img, params, out, max_w);
}

// Round 6
// 24.478 us; speedup vs baseline: 1.0148x; 1.0114x over previous
//
#include <hip/hip_runtime.h>

// Problem constants (from the reference file)
constexpr int kC = 3;
constexpr int kH = 2048;
constexpr int kW = 2048;
constexpr int kNB = 256;      // N_BOXES
constexpr int kHeight = 32;   // HEIGHT
constexpr int kWin = 416;     // staged x-window cap (floats, multiple of 4)

typedef float f32x4 __attribute__((ext_vector_type(4)));

// Kernel 1: per-box params -> d_ws (16 floats/box); widths_out -> out tail.
__global__ __launch_bounds__(256) void boxprep_kernel(
    const float* __restrict__ boxes,
    const float* __restrict__ scale,
    float* __restrict__ params,
    float* __restrict__ out_tail)
{
    const int b = threadIdx.x;            // 256 boxes, 1 block
    const float s = scale[0];
    const float* bx = boxes + b * 8;
    float p[8];
#pragma unroll
    for (int k = 0; k < 8; ++k) p[k] = bx[k] / s;

    const float hdx = p[4] - p[2], hdy = p[5] - p[3];
    const float h_dist = sqrtf(hdx * hdx + hdy * hdy);
    const float wdx = p[2] - p[0], wdy = p[3] - p[1];
    const float w_dist = sqrtf(wdx * wdx + wdy * wdy);
    const int width = (int)(32.0f * w_dist / fmaxf(h_dist, 1e-6f));
    const float curr_w = (float)width;
    const float inv_xden = 1.0f / fmaxf(curr_w - 1.0f, 1.0f);

    // x-window covering res_x range (axis-aligned boxes: [p0x, p1x]) + guard
    const float xlo = fminf(p[0], p[6]);
    const float xhi = fmaxf(p[2], p[4]);
    int wbase = (int)floorf(xlo) - 2;
    if (wbase < 0) wbase = 0;
    wbase &= ~3;                          // 16B-align the staging loads
    int wend = (int)ceilf(xhi) + 2;
    if (wend > kW - 1) wend = kW - 1;
    int wlen = wend - wbase + 1;
    wlen = (wlen + 3) & ~3;
    if (wbase + wlen > kW) wlen = kW - wbase;
    if (wlen > kWin) wlen = kWin;         // fallback path covers any overflow
    if (wlen < 4) wlen = 4;

    float* pp = params + b * 16;
#pragma unroll
    for (int k = 0; k < 8; ++k) pp[k] = p[k];
    pp[8]  = curr_w;
    pp[9]  = inv_xden;
    pp[10] = __int_as_float(wbase);
    pp[11] = __int_as_float(wlen);

    out_tail[b] = (float)(width / 8 * 8 + 8);
}

// Kernel 2: one block per (box b, row r). Stage the sampled image row window
// in LDS (coalesced), then per-column exact reference math; LDS fast path
// when (fiy == fiy0 && fix in window), global-gather fallback otherwise.
__global__ __launch_bounds__(256) void extract_kernel(
    const float* __restrict__ img,
    const float* __restrict__ params,
    float* __restrict__ out,
    int max_w)
{
    __shared__ float lds[3][kWin];

    const int r = blockIdx.x;
    const int b = blockIdx.y;
    const float* pp = params + b * 16;    // uniform -> scalar loads
    const float p0x = pp[0], p0y = pp[1];
    const float p1x = pp[2], p1y = pp[3];
    const float p2x = pp[4], p2y = pp[5];
    const float p3x = pp[6], p3y = pp[7];
    const float curr_w = pp[8];
    const float inv_xden = pp[9];
    const int wbase = __float_as_int(pp[10]);
    const int wlen  = __float_as_int(pp[11]);

    const float y = (float)r / 31.0f;
    const float omy = 1.0f - y;
    constexpr float invW1 = 1.0f / 2047.0f;

    // Row index at column 0 via the generic expression (x = 0).
    {
    }
    const float x0_ = 0.0f * inv_xden;
    const float omx0_ = 1.0f - x0_;
    const float w00_ = omx0_ * omy, w10_ = x0_ * omy, w11_ = x0_ * y, w01_ = omx0_ * y;
    const float ry0 = ((w00_ * p0y + w10_ * p1y) + w11_ * p2y) + w01_ * p3y;
    const float gr0 = ry0 * invW1 * 2.0f - 1.0f;
    const float fiy0 = rintf((gr0 + 1.0f) * 2047.0f * 0.5f);
    const bool stage_ok = (fiy0 >= 0.0f) && (fiy0 <= 2047.0f);
    const int iy0 = (int)fminf(fmaxf(fiy0, 0.0f), 2047.0f);

    // Stage the row window, 3 channels, coalesced 16B loads.
    const int nq_win = wlen >> 2;
#pragma unroll
    for (int ch = 0; ch < 3; ++ch) {
        const float* src = img + (size_t)ch * kH * kW + (size_t)iy0 * kW + wbase;
        for (int t4 = threadIdx.x; t4 < nq_win; t4 += 256) {
            *(f32x4*)&lds[ch][t4 * 4] = *(const f32x4*)&src[t4 * 4];
        }
    }
    __syncthreads();

    const size_t ch_stride = (size_t)kHeight * max_w;
    const size_t rowbase = ((size_t)b * (kC * kHeight) + (size_t)r) * (size_t)max_w;
    const float wlo = (float)wbase;
    const float whi = (float)(wbase + wlen);

    const int nq = max_w >> 2;
    for (int qi = threadIdx.x; qi < nq; qi += 256) {
        const int c0 = qi * 4;
        f32x4 o0 = {0.f, 0.f, 0.f, 0.f};
        f32x4 o1 = {0.f, 0.f, 0.f, 0.f};
        f32x4 o2 = {0.f, 0.f, 0.f, 0.f};

        if ((float)c0 < curr_w) {
#pragma unroll
            for (int j = 0; j < 4; ++j) {
                const float cf = (float)(c0 + j);
                if (cf < curr_w) {
                    const float x = cf * inv_xden;
                    const float omx = 1.0f - x;
                    const float w00 = omx * omy;
                    const float w10 = x * omy;
                    const float w11 = x * y;
                    const float w01 = omx * y;
                    const float res_x = ((w00 * p0x + w10 * p1x) + w11 * p2x) + w01 * p3x;
                    const float res_y = ((w00 * p0y + w10 * p1y) + w11 * p2y) + w01 * p3y;
                    const float grid_c = res_x * invW1 * 2.0f - 1.0f;
                    const float grid_r = res_y * invW1 * 2.0f - 1.0f;
                    const float fix = rintf((grid_c + 1.0f) * 2047.0f * 0.5f);
                    const float fiy = rintf((grid_r + 1.0f) * 2047.0f * 0.5f);

                    if (stage_ok && fiy == fiy0 && fix >= wlo && fix < whi) {
                        const int t = (int)fix - wbase;
                        o0[j] = lds[0][t];
                        o1[j] = lds[1][t];
                        o2[j] = lds[2][t];
                    } else {
                        const bool inb = (fix >= 0.0f) && (fix <= 2047.0f) &&
                                         (fiy >= 0.0f) && (fiy <= 2047.0f);
                        const int ixc = (int)fminf(fmaxf(fix, 0.0f), 2047.0f);
                        const int iyc = (int)fminf(fmaxf(fiy, 0.0f), 2047.0f);
                        const size_t ipix = (size_t)iyc * kW + (size_t)ixc;
                        o0[j] = inb ? img[ipix] : 0.0f;
                        o1[j] = inb ? img[(size_t)kH * kW + ipix] : 0.0f;
                        o2[j] = inb ? img[2 * (size_t)kH * kW + ipix] : 0.0f;
                    }
                }
            }
        }

        *(f32x4*)(out + rowbase + c0) = o0;
        *(f32x4*)(out + rowbase + ch_stride + c0) = o1;
        *(f32x4*)(out + rowbase + 2 * ch_stride + c0) = o2;
    }
}

extern "C" void kernel_launch(void* const* d_in, const int* in_sizes, int n_in,
                              void* d_out, int out_size, void* d_ws, size_t ws_size,
                              hipStream_t stream) {
    const float* img   = (const float*)d_in[0];
    const float* boxes = (const float*)d_in[1];
    const float* scale = (const float*)d_in[2];
    float* out = (float*)d_out;
    float* params = (float*)d_ws;         // 256 boxes * 16 floats = 16 KB

    // out_size = NB*C*HEIGHT*max_w + NB  ->  max_w recoverable (multiple of 8)
    const int max_w = (out_size - kNB) / (kNB * kC * kHeight);

    boxprep_kernel<<<1, kNB, 0, stream>>>(boxes, scale, params,
                                          out + (size_t)kNB * kC * kHeight * max_w);

    dim3 grid(kHeight, kNB);
    extract_kernel<<<grid, dim3(256, 1, 1), 0, stream>>>(img, params, out, max_w);
}